// Round 8
// baseline (1380.451 us; speedup 1.0000x reference)
//
#include <hip/hip_runtime.h>

// Problem constants: B=64, S=512, E=512, H=512, V=32000, T=2, L=1
// Output depends ONLY on batch sample 63 (lstm_out[-1] == last batch element).

typedef float f32x4 __attribute__((ext_vector_type(4)));
typedef unsigned long long u64;

#define NB 64   // persistent blocks for the recurrence

// LDS h-buffer swizzle: 32 groups of 16 floats, padded to stride 20 words
// (80 B = 5 banks*16B) -> float4 reads stay 16B-aligned, 16-way conflict -> 4-way.
#define HIDX(e) ((((e) >> 4) * 20) + ((e) & 15))

// ---------------------------------------------------------------------------
// Kernel 1': gather x rows: xbuf[t][:] = emb[sent[63][t]][:]  (1 MB copy).
// Replaces the 512x2048x512 xg GEMM (~150us) -- the projection itself is
// folded into the recurrence's poll shadow (see lstm_fused_k).
// ---------------------------------------------------------------------------
__global__ __launch_bounds__(256) void xgather_k(
    const int* __restrict__ sent, const float* __restrict__ emb,
    float* __restrict__ xbuf)
{
    __shared__ int idx[8];
    const int tid = threadIdx.x;
    const int t0 = blockIdx.x * 8;
    if (tid < 8) idx[tid] = sent[63 * 512 + t0 + tid];
    __syncthreads();
    // 8 rows x 128 float4 per block, 4 float4 per thread, coalesced per row.
    #pragma unroll
    for (int i = tid; i < 1024; i += 256) {
        const int r = i >> 7, c = i & 127;
        ((f32x4*)xbuf)[(size_t)(t0 + r) * 128 + c] =
            ((const f32x4*)emb)[(size_t)idx[r] * 128 + c];
    }
}

// ---------------------------------------------------------------------------
// Kernel 2: FUSED persistent batch-1 LSTM recurrence, 512 steps, 64 blocks
// x 256. Block b owns h-indices [b*8, b*8+8) -> 32 gate rows {q*512+b*8+j}.
//
// Handoff (PROVEN r0 protocol, byte-identical): h values travel as tagged
// 64-bit slots  slot = (u64)(t+1) << 32 | float_bits(h_t), relaxed
// agent-scope 8B atomic stores; readers poll slot[tid], slot[tid+256];
// two arrays ping-pong by step parity; no fences. Two barriers, hbuf
// broadcast, gacc LDS, gate tail on tid<8.
//
// FUSION (this round's single change): the x-projection
//   xg[t][g] = sum_e xbuf[t][e] * W_ih[g][e]
// is computed inline, BEFORE the poll, into xacc[4] (64 FMAs + 20 dwordx4
// L2 loads per thread). r7 proved the FMA/weight phase is not the critical
// path -- the poll spin slack absorbs it. A 4-float "+v" asm pins the
// computation before the volatile poll atomics; 4 floats survive the poll
// without spill (r0's xgp[4] precedent). Bias (b_ih+b_hh) moves to a
// 32-float LDS table added in the gate tail. Kernel 1 (xg GEMM) is GONE.
// ---------------------------------------------------------------------------
__global__ __launch_bounds__(256, 1) void lstm_fused_k(
    const float* __restrict__ h0, const float* __restrict__ c0,
    const float* __restrict__ W_hh, const float* __restrict__ W_ih,
    const float* __restrict__ xbuf,
    const float* __restrict__ b_ih, const float* __restrict__ b_hh,
    float* __restrict__ hs,
    u64* __restrict__ sA, u64* __restrict__ sB)
{
    __shared__ float hbuf[32 * 20];
    __shared__ float gacc[32];
    __shared__ float cbuf[8];
    __shared__ float bias[32];

    const int tid = threadIdx.x;
    const int b = blockIdx.x;
    const int cg = tid & 31;   // column group: 16 cols each
    const int rg = tid >> 5;   // row group: 4 rows each, 8 groups = 32 rows

    // Global gate-row indices for this thread's 4 rows.
    int grow[4];
    #pragma unroll
    for (int r = 0; r < 4; r++) {
        int rl = rg * 4 + r;                    // row_local in [0,32)
        grow[r] = (rl >> 3) * 512 + b * 8 + (rl & 7);
    }

    // Bias table for this block's 32 rows: bias[rl] matches gacc[rl].
    if (tid < 32) {
        int g = (tid >> 3) * 512 + b * 8 + (tid & 7);
        bias[tid] = b_ih[g] + b_hh[g];
    }
    if (tid < 8) cbuf[tid] = c0[63 * 512 + b * 8 + tid];
    __syncthreads();

    for (int t = 0; t < 512; t++) {
        // ---- x-projection in the poll shadow (h-independent) ----
        // 4 dwordx4 x-loads + 16 dwordx4 W_ih loads + 64 FMAs; the compiler
        // chunk-streams these from L2 exactly as it does the W_hh stream.
        float xacc[4];
        {
            f32x4 xv[4];
            #pragma unroll
            for (int cq = 0; cq < 4; cq++)
                xv[cq] = *(const f32x4*)&xbuf[(size_t)t * 512 + cg * 16 + cq * 4];
            #pragma unroll
            for (int r = 0; r < 4; r++) {
                float s = 0.f;
                #pragma unroll
                for (int cq = 0; cq < 4; cq++) {
                    f32x4 wv = *(const f32x4*)&W_ih[(size_t)grow[r] * 512 + cg * 16 + cq * 4];
                    s += wv.x * xv[cq].x;
                    s += wv.y * xv[cq].y;
                    s += wv.z * xv[cq].z;
                    s += wv.w * xv[cq].w;
                }
                xacc[r] = s;
            }
        }
        // Pin the x-projection BEFORE the poll (volatile asm cannot move
        // across the volatile atomic poll; keeps the stream in the shadow).
        asm volatile("" : "+v"(xacc[0]), "+v"(xacc[1]),
                          "+v"(xacc[2]), "+v"(xacc[3]));

        if (t == 0) {
            hbuf[HIDX(tid)]       = h0[63 * 512 + tid];
            hbuf[HIDX(tid + 256)] = h0[63 * 512 + tid + 256];
        } else {
            // Poll tagged slots of step t-1 (tag == t) in buffer (t-1)&1.
            u64* src = ((t - 1) & 1) ? sB : sA;
            u64* p0 = &src[tid];
            u64* p1 = &src[tid + 256];
            const unsigned int expt = (unsigned int)t;
            u64 v0, v1;
            for (;;) {
                v0 = __hip_atomic_load(p0, __ATOMIC_RELAXED, __HIP_MEMORY_SCOPE_AGENT);
                v1 = __hip_atomic_load(p1, __ATOMIC_RELAXED, __HIP_MEMORY_SCOPE_AGENT);
                if ((unsigned int)(v0 >> 32) == expt &&
                    (unsigned int)(v1 >> 32) == expt) break;
            }
            hbuf[HIDX(tid)]       = __uint_as_float((unsigned int)v0);
            hbuf[HIDX(tid + 256)] = __uint_as_float((unsigned int)v1);
        }
        __syncthreads();

        // h fragment from LDS.
        f32x4 hv[4];
        #pragma unroll
        for (int cq = 0; cq < 4; cq++)
            hv[cq] = *(const f32x4*)&hbuf[cg * 20 + cq * 4];

        // 4 rows x 16 cols of recurrent FMA; add the x-projection partial.
        float acc[4];
        #pragma unroll
        for (int r = 0; r < 4; r++) {
            float s = xacc[r];
            #pragma unroll
            for (int cq = 0; cq < 4; cq++) {
                f32x4 wv = *(const f32x4*)&W_hh[(size_t)grow[r] * 512 + cg * 16 + cq * 4];
                s += wv.x * hv[cq].x;
                s += wv.y * hv[cq].y;
                s += wv.z * hv[cq].z;
                s += wv.w * hv[cq].w;
            }
            acc[r] = s;
        }

        // Reduce over the 32 column-group lanes (xor masks <=16 stay in half-wave).
        #pragma unroll
        for (int r = 0; r < 4; r++) {
            #pragma unroll
            for (int m = 16; m >= 1; m >>= 1)
                acc[r] += __shfl_xor(acc[r], m, 64);
        }
        if (cg == 0) {
            #pragma unroll
            for (int r = 0; r < 4; r++)
                gacc[rg * 4 + r] = acc[r];   // gacc index == q*8 + j
        }
        __syncthreads();

        // Gate tail on lanes 0..7 (wave 0). Torch order: i, f, g, o.
        if (tid < 8) {
            float gi = gacc[tid]      + bias[tid];
            float gf = gacc[8 + tid]  + bias[8 + tid];
            float gc = gacc[16 + tid] + bias[16 + tid];
            float go = gacc[24 + tid] + bias[24 + tid];
            float ii = 1.f / (1.f + __expf(-gi));
            float ff = 1.f / (1.f + __expf(-gf));
            float cc = 1.f - 2.f / (__expf(2.f * gc) + 1.f);   // tanh
            float oo = 1.f / (1.f + __expf(-go));
            float cn = ff * cbuf[tid] + ii * cc;
            cbuf[tid] = cn;
            float th = 1.f - 2.f / (__expf(2.f * cn) + 1.f);   // tanh
            float hval = oo * th;

            // Publish FIRST (critical path), history store after.
            u64* dst = (t & 1) ? sB : sA;
            u64 pv =
                ((u64)(unsigned int)(t + 1) << 32) |
                (u64)__float_as_uint(hval);
            __hip_atomic_store(&dst[b * 8 + tid], pv,
                               __ATOMIC_RELAXED, __HIP_MEMORY_SCOPE_AGENT);

            hs[(size_t)t * 512 + b * 8 + tid] = hval;
        }
        // NO __threadfence, NO flag store.
    }
}

// ---------------------------------------------------------------------------
// Kernel 3: out[s][u] = hs[s] . W_lin[u] + b_lin[u], S=512, T=2. (unchanged)
// ---------------------------------------------------------------------------
__global__ __launch_bounds__(256) void final_linear_k(
    const float* __restrict__ hs, const float* __restrict__ W_lin,
    const float* __restrict__ b_lin, float* __restrict__ out)
{
    const int tid = threadIdx.x;
    const int wave = tid >> 6;
    const int lane = tid & 63;
    const int s = blockIdx.x * 4 + wave;
    const float* h = hs + (size_t)s * 512;
    float a0 = 0.f, a1 = 0.f;
    #pragma unroll
    for (int k0 = 0; k0 < 512; k0 += 64) {
        float hv = h[k0 + lane];
        a0 += hv * W_lin[k0 + lane];
        a1 += hv * W_lin[512 + k0 + lane];
    }
    #pragma unroll
    for (int m = 32; m >= 1; m >>= 1) {
        a0 += __shfl_xor(a0, m, 64);
        a1 += __shfl_xor(a1, m, 64);
    }
    if (lane == 0) {
        out[s * 2]     = a0 + b_lin[0];
        out[s * 2 + 1] = a1 + b_lin[1];
    }
}

// ---------------------------------------------------------------------------
extern "C" void kernel_launch(void* const* d_in, const int* in_sizes, int n_in,
                              void* d_out, int out_size, void* d_ws, size_t ws_size,
                              hipStream_t stream)
{
    const int*   sent  = (const int*)d_in[0];     // [64,512] int32
    const float* h0    = (const float*)d_in[1];   // [1,64,512]
    const float* c0    = (const float*)d_in[2];   // [1,64,512]
    const float* emb   = (const float*)d_in[3];   // [32000,512]
    const float* W_ih  = (const float*)d_in[4];   // [2048,512]
    const float* W_hh  = (const float*)d_in[5];   // [2048,512]
    const float* b_ih  = (const float*)d_in[6];   // [2048]
    const float* b_hh  = (const float*)d_in[7];   // [2048]
    const float* W_lin = (const float*)d_in[8];   // [2,512]
    const float* b_lin = (const float*)d_in[9];   // [2]
    float* out = (float*)d_out;                   // [512,2]

    char* ws = (char*)d_ws;
    float* xbuf = (float*)ws;                                 // 1 MB: [512,512]
    float* hs = (float*)(ws + 4 * 1024 * 1024);               // 1 MB: [512,512]
    u64* sA = (u64*)(ws + 5 * 1024 * 1024);                   // 4 KB
    u64* sB = (u64*)(ws + 5 * 1024 * 1024 + 4096);            // 4 KB

    // Clear slot tags (0 != any expected tag 1..512).
    hipMemsetAsync(sA, 0, 2 * 4096, stream);

    xgather_k<<<64, 256, 0, stream>>>(sent, emb, xbuf);
    lstm_fused_k<<<NB, 256, 0, stream>>>(h0, c0, W_hh, W_ih, xbuf,
                                         b_ih, b_hh, hs, sA, sB);
    final_linear_k<<<128, 256, 0, stream>>>(hs, W_lin, b_lin, out);
}

// Round 9
// 1141.489 us; speedup vs baseline: 1.2093x; 1.2093x over previous
//
#include <hip/hip_runtime.h>

// Problem constants: B=64, S=512, E=512, H=512, V=32000, T=2, L=1
// Output depends ONLY on batch sample 63 (lstm_out[-1] == last batch element).

typedef float f32x4 __attribute__((ext_vector_type(4)));
typedef unsigned long long u64;

#define NB 128  // persistent blocks: 4 h-values each (r3 scaling law inverted:
                // halves the per-block W_hh stream that r3 proved is on the
                // critical path; straggler cost grows only ~sqrt(log N))

// LDS h-buffer swizzle: 32 groups of 16 floats, padded to stride 20 words
// (80 B = 5 banks*16B) -> float4 reads stay 16B-aligned, 16-way conflict -> 4-way.
#define HIDX(e) ((((e) >> 4) * 20) + ((e) & 15))

// ---------------------------------------------------------------------------
// Kernel 1: xg[t][g] = sum_e emb[sent[63][t]][e] * W_ih[g][e] + b_ih[g]+b_hh[g]
// M=512 (t), N=2048 (g), K=512. Both operands K-major (NT GEMM).
// CHANGE: LDS pad 65->68 keeps every row 16B-aligned -> inner loop reads
// f32x4 (2 ds_read_b128 per k instead of 8 ds_read_b32). r8 measured this
// kernel at ~70us above floor (total-lstm: 167us vs 99us with gather-only).
// ---------------------------------------------------------------------------
__global__ __launch_bounds__(256) void xg_gemm_k(
    const int* __restrict__ sent, const float* __restrict__ emb,
    const float* __restrict__ W_ih, const float* __restrict__ b_ih,
    const float* __restrict__ b_hh, float* __restrict__ xg)
{
    __shared__ float As[16][68];   // [k][m], 68%4==0 -> rows 16B-aligned
    __shared__ float Bs[16][68];   // [k][n]
    __shared__ int aidx[64];
    const int tid = threadIdx.x;
    const int t0 = blockIdx.x * 64;
    const int n0 = blockIdx.y * 64;
    if (tid < 64) aidx[tid] = sent[63 * 512 + t0 + tid];
    __syncthreads();

    const int kk = tid & 15;   // k within tile
    const int mm = tid >> 4;   // 0..15
    const int tx = tid & 15, ty = tid >> 4;
    float acc[4][4] = {};

    for (int kb = 0; kb < 512; kb += 16) {
        #pragma unroll
        for (int j = 0; j < 4; j++) {
            int m = mm + j * 16;
            As[kk][m] = emb[(size_t)aidx[m] * 512 + kb + kk];
            Bs[kk][m] = W_ih[(size_t)(n0 + m) * 512 + kb + kk];
        }
        __syncthreads();
        #pragma unroll
        for (int k = 0; k < 16; k++) {
            // Vector LDS reads: av broadcast within ty-group (conflict-free),
            // bv 2-way aliased (free per m136).
            f32x4 av = *(const f32x4*)&As[k][ty * 4];
            f32x4 bv = *(const f32x4*)&Bs[k][tx * 4];
            #pragma unroll
            for (int i = 0; i < 4; i++)
                #pragma unroll
                for (int j = 0; j < 4; j++)
                    acc[i][j] += av[i] * bv[j];
        }
        __syncthreads();
    }

    #pragma unroll
    for (int i = 0; i < 4; i++) {
        int t = t0 + ty * 4 + i;
        #pragma unroll
        for (int j = 0; j < 4; j++) {
            int col = n0 + tx * 4 + j;
            xg[(size_t)t * 2048 + col] = acc[i][j] + b_ih[col] + b_hh[col];
        }
    }
}

// ---------------------------------------------------------------------------
// Kernel 2: persistent batch-1 LSTM recurrence, 512 steps, 128 blocks x 256.
// Block b owns h-indices [b*4, b*4+4) -> 16 gate rows {q*512 + b*4 + j}.
// Thread (cg=tid&31, rg=tid>>5) owns 2 rows (rl = rg*2+r), 16 cols each
// -> 8 dwordx4 W_hh loads/thread/step (HALF of r0's 16: the stream r3
// proved critical-path-resident at ~900cy per 16 loads).
//
// Handoff (PROVEN r0 protocol, byte-identical): h values travel as tagged
// 64-bit slots  slot = (u64)(t+1) << 32 | float_bits(h_t), relaxed
// agent-scope 8B atomic stores; readers poll slot[tid], slot[tid+256] (512
// slots, unchanged); two arrays ping-pong by step parity; no fences. Two
// barriers, hbuf broadcast, gacc LDS, gate tail on tid<4.
// ---------------------------------------------------------------------------
__global__ __launch_bounds__(256, 1) void lstm_seq_k(
    const float* __restrict__ h0, const float* __restrict__ c0,
    const float* __restrict__ W_hh, const float* __restrict__ xg,
    float* __restrict__ hs,
    u64* __restrict__ sA, u64* __restrict__ sB)
{
    __shared__ float hbuf[32 * 20];
    __shared__ float gacc[16];
    __shared__ float cbuf[4];

    const int tid = threadIdx.x;
    const int b = blockIdx.x;
    const int cg = tid & 31;   // column group: 16 cols each
    const int rg = tid >> 5;   // row group: 2 rows each, 8 groups = 16 rows

    // Global gate-row indices for this thread's 2 rows.
    // rl = rg*2 + r in [0,16); q = rl>>2; j = rl&3; gacc index == rl.
    int grow[2];
    #pragma unroll
    for (int r = 0; r < 2; r++) {
        int rl = rg * 2 + r;
        grow[r] = (rl >> 2) * 512 + b * 4 + (rl & 3);
    }

    if (tid < 4) cbuf[tid] = c0[63 * 512 + b * 4 + tid];
    __syncthreads();

    for (int t = 0; t < 512; t++) {
        // Prefetch xg for this step (independent of h -> overlaps the wait).
        float xgp[2];
        if (cg == 0) {
            #pragma unroll
            for (int r = 0; r < 2; r++)
                xgp[r] = xg[(size_t)t * 2048 + grow[r]];
        }

        if (t == 0) {
            hbuf[HIDX(tid)]       = h0[63 * 512 + tid];
            hbuf[HIDX(tid + 256)] = h0[63 * 512 + tid + 256];
        } else {
            // Poll tagged slots of step t-1 (tag == t) in buffer (t-1)&1.
            u64* src = ((t - 1) & 1) ? sB : sA;
            u64* p0 = &src[tid];
            u64* p1 = &src[tid + 256];
            const unsigned int expt = (unsigned int)t;
            u64 v0, v1;
            for (;;) {
                v0 = __hip_atomic_load(p0, __ATOMIC_RELAXED, __HIP_MEMORY_SCOPE_AGENT);
                v1 = __hip_atomic_load(p1, __ATOMIC_RELAXED, __HIP_MEMORY_SCOPE_AGENT);
                if ((unsigned int)(v0 >> 32) == expt &&
                    (unsigned int)(v1 >> 32) == expt) break;
            }
            hbuf[HIDX(tid)]       = __uint_as_float((unsigned int)v0);
            hbuf[HIDX(tid + 256)] = __uint_as_float((unsigned int)v1);
        }
        __syncthreads();

        // h fragment from LDS.
        f32x4 hv[4];
        #pragma unroll
        for (int cq = 0; cq < 4; cq++)
            hv[cq] = *(const f32x4*)&hbuf[cg * 20 + cq * 4];

        // 2 rows x 16 cols of FMA per thread (8 dwordx4 W_hh loads,
        // compiler chunk-streams from L2 -- half of r0's volume).
        float acc[2];
        #pragma unroll
        for (int r = 0; r < 2; r++) {
            float s = 0.f;
            #pragma unroll
            for (int cq = 0; cq < 4; cq++) {
                f32x4 wv = *(const f32x4*)&W_hh[(size_t)grow[r] * 512 + cg * 16 + cq * 4];
                s += wv.x * hv[cq].x;
                s += wv.y * hv[cq].y;
                s += wv.z * hv[cq].z;
                s += wv.w * hv[cq].w;
            }
            acc[r] = s;
        }

        // Reduce over the 32 column-group lanes (xor masks <=16 stay in half-wave).
        #pragma unroll
        for (int r = 0; r < 2; r++) {
            #pragma unroll
            for (int m = 16; m >= 1; m >>= 1)
                acc[r] += __shfl_xor(acc[r], m, 64);
        }
        if (cg == 0) {
            #pragma unroll
            for (int r = 0; r < 2; r++)
                gacc[rg * 2 + r] = acc[r] + xgp[r];   // gacc index == q*4 + j
        }
        __syncthreads();

        // Gate tail on lanes 0..3 (wave 0). Torch order: i, f, g, o.
        if (tid < 4) {
            float gi = gacc[tid];
            float gf = gacc[4 + tid];
            float gc = gacc[8 + tid];
            float go = gacc[12 + tid];
            float ii = 1.f / (1.f + __expf(-gi));
            float ff = 1.f / (1.f + __expf(-gf));
            float cc = 1.f - 2.f / (__expf(2.f * gc) + 1.f);   // tanh
            float oo = 1.f / (1.f + __expf(-go));
            float cn = ff * cbuf[tid] + ii * cc;
            cbuf[tid] = cn;
            float th = 1.f - 2.f / (__expf(2.f * cn) + 1.f);   // tanh
            float hval = oo * th;

            // Publish FIRST (critical path), history store after.
            u64* dst = (t & 1) ? sB : sA;
            u64 pv =
                ((u64)(unsigned int)(t + 1) << 32) |
                (u64)__float_as_uint(hval);
            __hip_atomic_store(&dst[b * 4 + tid], pv,
                               __ATOMIC_RELAXED, __HIP_MEMORY_SCOPE_AGENT);

            hs[(size_t)t * 512 + b * 4 + tid] = hval;
        }
        // NO __threadfence, NO flag store.
    }
}

// ---------------------------------------------------------------------------
// Kernel 3: out[s][u] = hs[s] . W_lin[u] + b_lin[u], S=512, T=2. (unchanged)
// ---------------------------------------------------------------------------
__global__ __launch_bounds__(256) void final_linear_k(
    const float* __restrict__ hs, const float* __restrict__ W_lin,
    const float* __restrict__ b_lin, float* __restrict__ out)
{
    const int tid = threadIdx.x;
    const int wave = tid >> 6;
    const int lane = tid & 63;
    const int s = blockIdx.x * 4 + wave;
    const float* h = hs + (size_t)s * 512;
    float a0 = 0.f, a1 = 0.f;
    #pragma unroll
    for (int k0 = 0; k0 < 512; k0 += 64) {
        float hv = h[k0 + lane];
        a0 += hv * W_lin[k0 + lane];
        a1 += hv * W_lin[512 + k0 + lane];
    }
    #pragma unroll
    for (int m = 32; m >= 1; m >>= 1) {
        a0 += __shfl_xor(a0, m, 64);
        a1 += __shfl_xor(a1, m, 64);
    }
    if (lane == 0) {
        out[s * 2]     = a0 + b_lin[0];
        out[s * 2 + 1] = a1 + b_lin[1];
    }
}

// ---------------------------------------------------------------------------
extern "C" void kernel_launch(void* const* d_in, const int* in_sizes, int n_in,
                              void* d_out, int out_size, void* d_ws, size_t ws_size,
                              hipStream_t stream)
{
    const int*   sent  = (const int*)d_in[0];     // [64,512] int32
    const float* h0    = (const float*)d_in[1];   // [1,64,512]
    const float* c0    = (const float*)d_in[2];   // [1,64,512]
    const float* emb   = (const float*)d_in[3];   // [32000,512]
    const float* W_ih  = (const float*)d_in[4];   // [2048,512]
    const float* W_hh  = (const float*)d_in[5];   // [2048,512]
    const float* b_ih  = (const float*)d_in[6];   // [2048]
    const float* b_hh  = (const float*)d_in[7];   // [2048]
    const float* W_lin = (const float*)d_in[8];   // [2,512]
    const float* b_lin = (const float*)d_in[9];   // [2]
    float* out = (float*)d_out;                   // [512,2]

    char* ws = (char*)d_ws;
    float* xg = (float*)ws;                                   // 4 MB: [512,2048]
    float* hs = (float*)(ws + 4 * 1024 * 1024);               // 1 MB: [512,512]
    u64* sA = (u64*)(ws + 5 * 1024 * 1024);                   // 4 KB
    u64* sB = (u64*)(ws + 5 * 1024 * 1024 + 4096);            // 4 KB

    // Clear slot tags (0 != any expected tag 1..512).
    hipMemsetAsync(sA, 0, 2 * 4096, stream);

    dim3 g1(8, 32);
    xg_gemm_k<<<g1, 256, 0, stream>>>(sent, emb, W_ih, b_ih, b_hh, xg);
    lstm_seq_k<<<NB, 256, 0, stream>>>(h0, c0, W_hh, xg, hs, sA, sB);
    final_linear_k<<<128, 256, 0, stream>>>(hs, W_lin, b_lin, out);
}